// Round 1
// baseline (113.529 us; speedup 1.0000x reference)
//
#include <hip/hip_runtime.h>
#include <hip/hip_bf16.h>

// ViT patch-embed + LN + head — but the output only depends on the CLS token:
//   tokens[:,0,:] = cls_token + pos_embed[:,0,:]   (batch-independent!)
//   LayerNorm is per-token, head reads only normed[:,0]
// => all 128 output rows are identical; x and patch_w are dead inputs.
//
// One kernel: grid = 1000 classes, 256 threads/block.
//  - each block recomputes LN of the 1024-dim CLS vector (L2-cached inputs)
//  - dots with head_w[c,:] (float4 loads, shuffle reduce)
//  - threads 0..127 broadcast the scalar to out[b*1000 + c]

#define DIM 1024
#define NUM_CLASSES 1000
#define BATCH 128
#define LN_EPS 1e-5f

__global__ __launch_bounds__(256) void vit_cls_head(
    const float* __restrict__ cls,   // (1,1,1024)
    const float* __restrict__ pos,   // (1,197,1024) — we use row 0
    const float* __restrict__ ln_g,  // (1024)
    const float* __restrict__ ln_b,  // (1024)
    const float* __restrict__ head_w,// (1000,1024)
    const float* __restrict__ head_b,// (1000)
    float* __restrict__ out)         // (128,1000)
{
    const int c = blockIdx.x;     // class index
    const int t = threadIdx.x;    // 0..255, each owns 4 elems of the 1024-vec
    const int lane = t & 63;
    const int wave = t >> 6;      // 0..3

    __shared__ float red[8];
    __shared__ float bcast;

    // token 0 = cls + pos[0]
    const float4 cv = reinterpret_cast<const float4*>(cls)[t];
    const float4 pv = reinterpret_cast<const float4*>(pos)[t];
    const float v0 = cv.x + pv.x;
    const float v1 = cv.y + pv.y;
    const float v2 = cv.z + pv.z;
    const float v3 = cv.w + pv.w;

    float s  = v0 + v1 + v2 + v3;
    float s2 = v0*v0 + v1*v1 + v2*v2 + v3*v3;

    // wave(64) shuffle reduce
    #pragma unroll
    for (int off = 32; off > 0; off >>= 1) {
        s  += __shfl_down(s,  off, 64);
        s2 += __shfl_down(s2, off, 64);
    }
    if (lane == 0) { red[wave] = s; red[4 + wave] = s2; }
    __syncthreads();

    __shared__ float mu_s, rs_s;
    if (t == 0) {
        const float S  = red[0] + red[1] + red[2] + red[3];
        const float S2 = red[4] + red[5] + red[6] + red[7];
        const float mu = S * (1.0f / DIM);
        const float var = S2 * (1.0f / DIM) - mu * mu;
        mu_s = mu;
        rs_s = rsqrtf(var + LN_EPS);
    }
    __syncthreads();
    const float mu = mu_s;
    const float rs = rs_s;

    const float4 gv = reinterpret_cast<const float4*>(ln_g)[t];
    const float4 bv = reinterpret_cast<const float4*>(ln_b)[t];
    const float n0 = (v0 - mu) * rs * gv.x + bv.x;
    const float n1 = (v1 - mu) * rs * gv.y + bv.y;
    const float n2 = (v2 - mu) * rs * gv.z + bv.z;
    const float n3 = (v3 - mu) * rs * gv.w + bv.w;

    // dot with head_w row c
    const float4 wv = reinterpret_cast<const float4*>(head_w + (size_t)c * DIM)[t];
    float d = n0*wv.x + n1*wv.y + n2*wv.z + n3*wv.w;
    #pragma unroll
    for (int off = 32; off > 0; off >>= 1) d += __shfl_down(d, off, 64);
    if (lane == 0) red[wave] = d;
    __syncthreads();
    if (t == 0) bcast = red[0] + red[1] + red[2] + red[3] + head_b[c];
    __syncthreads();

    const float result = bcast;
    if (t < BATCH) out[(size_t)t * NUM_CLASSES + c] = result;
}

extern "C" void kernel_launch(void* const* d_in, const int* in_sizes, int n_in,
                              void* d_out, int out_size, void* d_ws, size_t ws_size,
                              hipStream_t stream) {
    // input order: x, patch_w, patch_b, cls_token, pos_embed, ln_g, ln_b, head_w, head_b
    const float* cls    = (const float*)d_in[3];
    const float* pos    = (const float*)d_in[4];
    const float* ln_g   = (const float*)d_in[5];
    const float* ln_b   = (const float*)d_in[6];
    const float* head_w = (const float*)d_in[7];
    const float* head_b = (const float*)d_in[8];
    float* out = (float*)d_out;

    vit_cls_head<<<NUM_CLASSES, 256, 0, stream>>>(cls, pos, ln_g, ln_b,
                                                  head_w, head_b, out);
}